// Round 16
// baseline (80.530 us; speedup 1.0000x reference)
//
#include <hip/hip_runtime.h>
#include <cmath>

#define HW   16384
#define Wd   128
#define Hd   128
#define NB   4

typedef __attribute__((ext_vector_type(8))) _Float16 h16x8;
typedef __attribute__((ext_vector_type(4))) float f32x4;
typedef __attribute__((ext_vector_type(4))) unsigned int u32x4;

__device__ inline unsigned short f2h(float f) {
    _Float16 h = (_Float16)f;
    return __builtin_bit_cast(unsigned short, h);
}
__device__ inline _Float16 u2h(unsigned short u) {
    return __builtin_bit_cast(_Float16, u);
}

// ---------- fused prep: weight repacks (fp16 MFMA A-frag layout) + bias + NHWC transposes ----------
__device__ inline void repack_one(int idx, const float* __restrict__ s1, const float* __restrict__ s2,
                                  int Osplit, int O, int CIN, int KS, unsigned short* __restrict__ dst) {
    int e    = idx & 7;
    int lane = (idx >> 3) & 63;
    int ks   = (idx >> 9) % KS;
    int m    = (idx / (512 * KS)) & 3;
    int k    = idx / (2048 * KS);
    int oc = m * 16 + (lane & 15);
    int c  = ks * 32 + (lane >> 4) * 8 + e;
    float v = 0.f;
    if (oc < O && c < CIN)
        v = (oc < Osplit) ? s1[((size_t)oc * CIN + c) * 9 + k]
                          : s2[((size_t)(oc - Osplit) * CIN + c) * 9 + k];
    dst[idx] = f2h(v);
}

__global__ __launch_bounds__(256) void prep(
    const float* __restrict__ input, const float* __restrict__ offset,
    const float* __restrict__ w_off1, const float* __restrict__ w_off2,
    const float* __restrict__ b_off1, const float* __restrict__ b_off2,
    const float* __restrict__ w1, const float* __restrict__ w2, const float* __restrict__ w_last,
    unsigned short* __restrict__ xn, unsigned short* __restrict__ offn,
    unsigned short* __restrict__ wfo, unsigned short* __restrict__ wf1,
    unsigned short* __restrict__ wf2, unsigned short* __restrict__ wfl,
    float* __restrict__ bias54)
{
    int blk = blockIdx.x;
    if (blk < 512) {
        int t = blk * 256 + threadIdx.x;
        if (t < 65536) {
            int b = t >> 14, p = t & 16383;
            const float* s = input + ((size_t)b * 64) * HW + p;
            unsigned short* d = xn + (size_t)t * 64;
#pragma unroll
            for (int g = 0; g < 8; g++) {
                unsigned short pk[8];
#pragma unroll
                for (int e = 0; e < 8; e++) pk[e] = f2h(s[(size_t)(g * 8 + e) * HW]);
                *(u32x4*)(d + g * 8) = *(u32x4*)pk;
            }
        } else {
            int u = t - 65536;
            int b = u >> 14, p = u & 16383;
            const float* s = offset + ((size_t)b * 32) * HW + p;
            unsigned short* d = offn + (size_t)u * 32;
#pragma unroll
            for (int g = 0; g < 4; g++) {
                unsigned short pk[8];
#pragma unroll
                for (int e = 0; e < 8; e++) pk[e] = f2h(s[(size_t)(g * 8 + e) * HW]);
                *(u32x4*)(d + g * 8) = *(u32x4*)pk;
            }
        }
    } else {
        int u = (blk - 512) * 256 + threadIdx.x;
        if (u < 18432)        repack_one(u, w_off1, w_off1, 27, 27, 32, 1, wfo);
        else if (u < 36864)   repack_one(u - 18432, w_off2, w_off2, 27, 27, 32, 1, wfo + 18432);
        else if (u < 73728)   repack_one(u - 36864, w1, w1, 64, 64, 64, 2, wf1);
        else if (u < 110592)  repack_one(u - 73728, w2, w2, 64, 64, 64, 2, wf2);
        else if (u < 147456)  repack_one(u - 110592, w_last, w_last, 64, 64, 64, 2, wfl);
        else if (u < 147510) {
            int j = u - 147456;
            bias54[j] = (j < 27) ? b_off1[j] : b_off2[j - 27];
        }
    }
}

// ---------- conv3x3 CIN=64 (final conv), LDS-staged window, 8 waves kh-split ----------
__global__ __launch_bounds__(512, 8) void conv_stage64(
    const unsigned short* __restrict__ xn, const unsigned short* __restrict__ wf,
    const float* __restrict__ bias, float* __restrict__ out)
{
    __shared__ __align__(16) unsigned short stage[198 * 64];   // 3x66 px x 64ch
    int lb = ((blockIdx.x & 7) << 7) | (blockIdx.x >> 3);
    int t = threadIdx.x;
    int pxbase = lb * 64;
    int b = pxbase >> 14;
    int pbase = pxbase & 16383;
    int rowbase = pbase >> 7, colbase = pbase & 127;
    const unsigned short* xb = xn + ((size_t)(b << 14)) * 64;

    for (int q = t; q < 1584; q += 512) {
        int ps = q >> 3, j = q & 7;
        int ly = ps / 66, lx = ps - ly * 66;
        int y = rowbase - 1 + ly, x = colbase - 1 + lx;
        bool ok = (y >= 0) & (y < Hd) & (x >= 0) & (x < Wd);
        u32x4 v = {0, 0, 0, 0};
        if (ok) v = *(const u32x4*)(xb + ((size_t)(y * Wd + x)) * 64 + j * 8);
        *(u32x4*)(stage + ps * 64 + ((j ^ (ps & 7)) << 3)) = v;
    }
    __syncthreads();

    int lane = t & 63;
    int wave = t >> 6;
    int kh = wave >> 2;
    int wv = wave & 3;
    int sp = wv * 16 + (lane & 15);
    int px = pxbase + sp;
    int p = px & 16383;
    int cg = lane >> 4;
    int cch = kh * 4 + cg;

    const h16x8* wfv = (const h16x8*)wf;
    f32x4 acc[4];
#pragma unroll
    for (int m = 0; m < 4; m++) acc[m] = (f32x4){0.f, 0.f, 0.f, 0.f};

#pragma unroll
    for (int k = 0; k < 9; k++) {
        int ps = (k / 3) * 66 + sp + (k % 3);
        h16x8 bq = *(const h16x8*)(stage + ps * 64 + ((cch ^ (ps & 7)) << 3));
        h16x8 aF[4];
#pragma unroll
        for (int m = 0; m < 4; m++)
            aF[m] = wfv[((k * 4 + m) * 2 + kh) * 64 + lane];
#pragma unroll
        for (int m = 0; m < 4; m++)
            acc[m] = __builtin_amdgcn_mfma_f32_16x16x32_f16(aF[m], bq, acc[m], 0, 0, 0);
    }

    __syncthreads();                 // stage reads done; red aliases stage
    float* red = (float*)stage;
    if (kh == 1) {
#pragma unroll
        for (int m = 0; m < 4; m++)
#pragma unroll
            for (int j = 0; j < 4; j++)
                red[(m * 4 + j) * 256 + wv * 64 + lane] = acc[m][j];
    }
    __syncthreads();
    if (kh == 0) {
#pragma unroll
        for (int m = 0; m < 4; m++) {
            int ocb = m * 16 + cg * 4;
#pragma unroll
            for (int r = 0; r < 4; r++) {
                int oc = ocb + r;
                float v = acc[m][r] + red[(m * 4 + r) * 256 + wv * 64 + lane] + bias[oc];
                out[((size_t)b * 64 + oc) * HW + p] = v;
            }
        }
    }
}

// ---------- DCNv2 sampling helpers ----------
struct Tap { float w00, w01, w10, w11; int o00, o01, o10, o11; };

__device__ inline Tap mkparams(float oy, float ox, float mv, int row, int col, int k) {
    Tap P;
    float mk = 1.f / (1.f + __expf(-mv));
    float ys = (float)(row + k / 3 - 1) + oy;
    float xs = (float)(col + k % 3 - 1) + ox;
    float y0f = floorf(ys), x0f = floorf(xs);
    float fy = ys - y0f, fx = xs - x0f;
    int y0 = (int)y0f, x0 = (int)x0f;
    int y1 = y0 + 1, x1 = x0 + 1;
    bool vy0 = (y0 >= 0) & (y0 < Hd);
    bool vy1 = (y1 >= 0) & (y1 < Hd);
    bool vx0 = (x0 >= 0) & (x0 < Wd);
    bool vx1 = (x1 >= 0) & (x1 < Wd);
    P.w00 = (vy0 && vx0) ? (1.f - fy) * (1.f - fx) * mk : 0.f;
    P.w01 = (vy0 && vx1) ? (1.f - fy) * fx * mk : 0.f;
    P.w10 = (vy1 && vx0) ? fy * (1.f - fx) * mk : 0.f;
    P.w11 = (vy1 && vx1) ? fy * fx * mk : 0.f;
    int iy0 = min(max(y0, 0), Hd - 1) * Wd;
    int iy1 = min(max(y1, 0), Hd - 1) * Wd;
    int ix0 = min(max(x0, 0), Wd - 1);
    int ix1 = min(max(x1, 0), Wd - 1);
    P.o00 = iy0 + ix0; P.o01 = iy0 + ix1; P.o10 = iy1 + ix0; P.o11 = iy1 + ix1;
    return P;
}

// ---------- DCNv2 with FUSED offset-conv, phase-packed schedule ----------
// LDS: stage 62.7KB (slots 0..489); offstage aliases slots 0..98; omt DEDICATED 6.9KB.
// A: stage offn window + main slots 99..489   (one barrier)
// B: offset conv, ALL 8 waves (m = wave>>2)   (one barrier)
// C: taps from omt + stage main slots 0..98   (one barrier)
// main loop / reduce / epilogue unchanged from R15.
// EPI 0: leaky -> outn (NHWC fp16). EPI 1: +resid(NCHW fp32) -> outn (NHWC fp16).
template<int EPI>
__global__ __launch_bounds__(512, 4) void dcn_fused(
    const unsigned short* __restrict__ xn, const unsigned short* __restrict__ offn,
    const unsigned short* __restrict__ wfo, const float* __restrict__ obias,
    const unsigned short* __restrict__ wf, const float* __restrict__ bias,
    const float* __restrict__ resid, unsigned short* __restrict__ outn)
{
    __shared__ __align__(16) unsigned short stage[490 * 64];  // 62.7KB main window
    __shared__ unsigned twp0[576], twp1[576];   // fp16 weight pairs
    __shared__ unsigned tap0[576], tap1[576];   // addr-code pairs
    __shared__ __align__(16) float omt[27 * 64];              // dedicated (no alias)

    unsigned short* offstage = stage;           // 198*32 ush = 12672B = slots 0..98

    int lb = ((blockIdx.x & 7) << 7) | (blockIdx.x >> 3);
    int t = threadIdx.x;
    int pxbase = lb * 64;
    int b = pxbase >> 14;
    int pbase = pxbase & 16383;
    int rowbase = pbase >> 7;
    int colbase = pbase & 127;
    int ybase = rowbase - 3;
    int xbase = colbase - 3;
    const unsigned short* xb = xn + ((size_t)(b << 14)) * 64;
    const unsigned short* ob = offn + ((size_t)(b << 14)) * 32;

    // ---- phase A: offn window (792) + main slots 99..489 (3128) ----
    for (int q = t; q < 3920; q += 512) {
        if (q < 792) {
            int ps = q >> 2, j = q & 3;
            int ly = ps / 66, lx = ps - ly * 66;
            int y = rowbase - 1 + ly, x = colbase - 1 + lx;
            bool ok = (y >= 0) & (y < Hd) & (x >= 0) & (x < Wd);
            u32x4 v = {0, 0, 0, 0};
            if (ok) v = *(const u32x4*)(ob + ((size_t)(y * Wd + x)) * 32 + j * 8);
            *(u32x4*)(offstage + ps * 32 + ((j ^ (ps & 3)) << 3)) = v;
        } else {
            int qq = q - 792;
            int ps = 99 + (qq >> 3), j = qq & 7;
            int ly = ps / 70, lx = ps - ly * 70;
            int y = min(max(ybase + ly, 0), Hd - 1);
            int x = min(max(xbase + lx, 0), Wd - 1);
            u32x4 v = *(const u32x4*)(xb + ((size_t)(y * Wd + x)) * 64 + j * 8);
            *(u32x4*)(stage + ps * 64 + ((j ^ (ps & 7)) << 3)) = v;
        }
    }
    __syncthreads();

    int lane = t & 63;
    int wave = t >> 6;

    // ---- phase B: offset conv, all 8 waves (1 MFMA/tap each) ----
    {
        int m = wave >> 2;
        int osp = (wave & 3) * 16 + (lane & 15);
        int cg4 = lane >> 4;
        const h16x8* wfvo = (const h16x8*)wfo;
        f32x4 oacc = (f32x4){0.f, 0.f, 0.f, 0.f};
#pragma unroll
        for (int k = 0; k < 9; k++) {
            int ps = (k / 3) * 66 + osp + (k % 3);
            h16x8 bq = *(const h16x8*)(offstage + ps * 32 + ((cg4 ^ (ps & 3)) << 3));
            h16x8 aF = wfvo[(k * 4 + m) * 64 + lane];
            oacc = __builtin_amdgcn_mfma_f32_16x16x32_f16(aF, bq, oacc, 0, 0, 0);
        }
        int ocb = m * 16 + cg4 * 4;
#pragma unroll
        for (int r = 0; r < 4; r++) {
            int oc = ocb + r;
            if (oc < 27) omt[oc * 64 + osp] = oacc[r] + obias[oc];
        }
    }
    __syncthreads();

    // ---- phase C: taps (576) + main slots 0..98 (792) ----
    for (int q = t; q < 1368; q += 512) {
        if (q < 576) {
            int s = q;
            int k = s >> 6, sp2 = s & 63;
            int row = rowbase, col = colbase + sp2;
            float oy = omt[(2 * k) * 64 + sp2];
            float ox = omt[(2 * k + 1) * 64 + sp2];
            float mv = omt[(18 + k) * 64 + sp2];
            Tap P = mkparams(oy, ox, mv, row, col, k);

            unsigned a[4];
            int oo[4] = {P.o00, P.o01, P.o10, P.o11};
#pragma unroll
            for (int c = 0; c < 4; c++) {
                int o = oo[c];
                int y = o >> 7, x = o & 127;
                int ly = y - ybase, lx = x - xbase;
                bool inw = ((unsigned)ly < 7u) & ((unsigned)lx < 70u);
                int ps = min(max(ly, 0), 6) * 70 + min(max(lx, 0), 69);
                a[c] = inw ? (unsigned)((ps << 3) | (ps & 7)) : (0x8000u | (unsigned)o);
            }
            twp0[s] = (unsigned)f2h(P.w00) | ((unsigned)f2h(P.w01) << 16);
            twp1[s] = (unsigned)f2h(P.w10) | ((unsigned)f2h(P.w11) << 16);
            tap0[s] = a[0] | (a[1] << 16);
            tap1[s] = a[2] | (a[3] << 16);
        } else {
            int qq = q - 576;
            int ps = qq >> 3, j = qq & 7;      // slots 0..98
            int ly = ps / 70, lx = ps - ly * 70;
            int y = min(max(ybase + ly, 0), Hd - 1);
            int x = min(max(xbase + lx, 0), Wd - 1);
            u32x4 v = *(const u32x4*)(xb + ((size_t)(y * Wd + x)) * 64 + j * 8);
            *(u32x4*)(stage + ps * 64 + ((j ^ (ps & 7)) << 3)) = v;
        }
    }
    __syncthreads();

    int kh = wave >> 2;
    int wv = wave & 3;
    int sp = wv * 16 + (lane & 15);
    int px = pxbase + sp;
    int p = px & 16383;
    int cg = lane >> 4;
    int c0 = kh * 32 + cg * 8;
    int cch = kh * 4 + cg;

    const h16x8* wfv = (const h16x8*)wf;

    f32x4 acc[4];
#pragma unroll
    for (int m = 0; m < 4; m++) acc[m] = (f32x4){0.f, 0.f, 0.f, 0.f};

#pragma unroll
    for (int k = 0; k < 9; k++) {
        int s = k * 64 + sp;
        unsigned a01 = tap0[s], a23 = tap1[s];
        unsigned w01 = twp0[s], w23 = twp1[s];

        unsigned code[4] = { a01 & 0xffffu, a01 >> 16, a23 & 0xffffu, a23 >> 16 };
        h16x8 gc[4];
#pragma unroll
        for (int c = 0; c < 4; c++)
            gc[c] = *(const h16x8*)((const char*)stage + (((code[c] & 0xFFFu) ^ (unsigned)cch) << 4));

        if (__builtin_expect((a01 | a23) & 0x80008000u, 0)) {
#pragma unroll
            for (int c = 0; c < 4; c++)
                if (code[c] & 0x8000u)
                    gc[c] = *(const h16x8*)(xb + (size_t)(code[c] & 0x7fffu) * 64 + c0);
        }

        _Float16 h00 = u2h((unsigned short)(w01 & 0xffffu));
        _Float16 h01 = u2h((unsigned short)(w01 >> 16));
        _Float16 h10 = u2h((unsigned short)(w23 & 0xffffu));
        _Float16 h11 = u2h((unsigned short)(w23 >> 16));
        h16x8 bF = gc[0] * h00;
        bF = gc[1] * h01 + bF;
        bF = gc[2] * h10 + bF;
        bF = gc[3] * h11 + bF;

        h16x8 aF[4];
#pragma unroll
        for (int m = 0; m < 4; m++)
            aF[m] = wfv[((k * 4 + m) * 2 + kh) * 64 + lane];
#pragma unroll
        for (int m = 0; m < 4; m++)
            acc[m] = __builtin_amdgcn_mfma_f32_16x16x32_f16(aF[m], bF, acc[m], 0, 0, 0);
    }

    __syncthreads();
    float* red = (float*)stage;
    if (kh == 1) {
#pragma unroll
        for (int m = 0; m < 4; m++)
#pragma unroll
            for (int j = 0; j < 4; j++)
                red[(m * 4 + j) * 256 + wv * 64 + lane] = acc[m][j];
    }
    __syncthreads();
    if (kh == 0) {
        unsigned short* drow = outn + (size_t)px * 64;
#pragma unroll
        for (int m = 0; m < 4; m++) {
            int ocb = m * 16 + cg * 4;
            unsigned short pk[4];
#pragma unroll
            for (int r = 0; r < 4; r++) {
                int oc = ocb + r;
                float v = acc[m][r] + red[(m * 4 + r) * 256 + wv * 64 + lane] + bias[oc];
                if (EPI == 0) v = (v >= 0.f) ? v : 0.01f * v;
                if (EPI == 1) v += resid[((size_t)b * 64 + oc) * HW + p];
                pk[r] = f2h(v);
            }
            *(ushort4*)(drow + ocb) = *(ushort4*)pk;
        }
    }
}

extern "C" void kernel_launch(void* const* d_in, const int* in_sizes, int n_in,
                              void* d_out, int out_size, void* d_ws, size_t ws_size,
                              hipStream_t stream)
{
    const float* input  = (const float*)d_in[0];
    const float* offset = (const float*)d_in[1];
    const float* w_off1 = (const float*)d_in[2];
    const float* b_off1 = (const float*)d_in[3];
    const float* w1     = (const float*)d_in[4];
    const float* b1     = (const float*)d_in[5];
    const float* w_off2 = (const float*)d_in[6];
    const float* b_off2 = (const float*)d_in[7];
    const float* w2     = (const float*)d_in[8];
    const float* b2     = (const float*)d_in[9];
    const float* w_last = (const float*)d_in[10];
    const float* b_last = (const float*)d_in[11];
    float* out = (float*)d_out;

    unsigned short* xn   = (unsigned short*)d_ws;          // 4,194,304 ush
    unsigned short* offn = xn + 4194304;                   // 2,097,152 ush
    unsigned short* x1n  = offn + 2097152;                 // 4,194,304 ush
    unsigned short* x2n  = x1n + 4194304;                  // 4,194,304 ush
    unsigned short* wfo  = x2n + 4194304;                  // 36,864 ush (two 27-oc sets)
    unsigned short* wf1  = wfo + 36864;                    // 36,864 ush
    unsigned short* wf2  = wf1 + 36864;                    // 36,864 ush
    unsigned short* wfl  = wf2 + 36864;                    // 36,864 ush
    float* bias54 = (float*)(wfl + 36864);                 // 64 f

    prep<<<dim3(1089), 256, 0, stream>>>(input, offset, w_off1, w_off2, b_off1, b_off2,
                                         w1, w2, w_last, xn, offn, wfo, wf1, wf2, wfl, bias54);

    // DCN 1 (fused offset-conv set 0): sample xn, leaky -> x1n
    dcn_fused<0><<<dim3(1024), 512, 0, stream>>>(xn, offn, wfo, bias54,
                                                 wf1, b1, nullptr, x1n);
    // DCN 2 (fused offset-conv set 1): sample x1n, + input residual -> x2n
    dcn_fused<1><<<dim3(1024), 512, 0, stream>>>(x1n, offn, wfo + 18432, bias54 + 27,
                                                 wf2, b2, input, x2n);
    // final conv
    conv_stage64<<<dim3(1024), 512, 0, stream>>>(x2n, wfl, b_last, out);
}

// Round 17
// 79.173 us; speedup vs baseline: 1.0171x; 1.0171x over previous
//
#include <hip/hip_runtime.h>
#include <cmath>

#define HW   16384
#define Wd   128
#define Hd   128
#define NB   4

typedef __attribute__((ext_vector_type(8))) _Float16 h16x8;
typedef __attribute__((ext_vector_type(4))) float f32x4;
typedef __attribute__((ext_vector_type(4))) unsigned int u32x4;

__device__ inline unsigned short f2h(float f) {
    _Float16 h = (_Float16)f;
    return __builtin_bit_cast(unsigned short, h);
}
__device__ inline _Float16 u2h(unsigned short u) {
    return __builtin_bit_cast(_Float16, u);
}

// ---------- fused prep: weight repacks (fp16 MFMA A-frag layout) + bias + NHWC transposes ----------
__device__ inline void repack_one(int idx, const float* __restrict__ s1, const float* __restrict__ s2,
                                  int Osplit, int O, int CIN, int KS, unsigned short* __restrict__ dst) {
    int e    = idx & 7;
    int lane = (idx >> 3) & 63;
    int ks   = (idx >> 9) % KS;
    int m    = (idx / (512 * KS)) & 3;
    int k    = idx / (2048 * KS);
    int oc = m * 16 + (lane & 15);
    int c  = ks * 32 + (lane >> 4) * 8 + e;
    float v = 0.f;
    if (oc < O && c < CIN)
        v = (oc < Osplit) ? s1[((size_t)oc * CIN + c) * 9 + k]
                          : s2[((size_t)(oc - Osplit) * CIN + c) * 9 + k];
    dst[idx] = f2h(v);
}

__global__ __launch_bounds__(256) void prep(
    const float* __restrict__ input, const float* __restrict__ offset,
    const float* __restrict__ w_off1, const float* __restrict__ w_off2,
    const float* __restrict__ b_off1, const float* __restrict__ b_off2,
    const float* __restrict__ w1, const float* __restrict__ w2, const float* __restrict__ w_last,
    unsigned short* __restrict__ xn, unsigned short* __restrict__ offn,
    unsigned short* __restrict__ wfo, unsigned short* __restrict__ wf1,
    unsigned short* __restrict__ wf2, unsigned short* __restrict__ wfl,
    float* __restrict__ bias54)
{
    int blk = blockIdx.x;
    if (blk < 512) {
        int t = blk * 256 + threadIdx.x;
        if (t < 65536) {
            int b = t >> 14, p = t & 16383;
            const float* s = input + ((size_t)b * 64) * HW + p;
            unsigned short* d = xn + (size_t)t * 64;
#pragma unroll
            for (int g = 0; g < 8; g++) {
                unsigned short pk[8];
#pragma unroll
                for (int e = 0; e < 8; e++) pk[e] = f2h(s[(size_t)(g * 8 + e) * HW]);
                *(u32x4*)(d + g * 8) = *(u32x4*)pk;
            }
        } else {
            int u = t - 65536;
            int b = u >> 14, p = u & 16383;
            const float* s = offset + ((size_t)b * 32) * HW + p;
            unsigned short* d = offn + (size_t)u * 32;
#pragma unroll
            for (int g = 0; g < 4; g++) {
                unsigned short pk[8];
#pragma unroll
                for (int e = 0; e < 8; e++) pk[e] = f2h(s[(size_t)(g * 8 + e) * HW]);
                *(u32x4*)(d + g * 8) = *(u32x4*)pk;
            }
        }
    } else {
        int u = (blk - 512) * 256 + threadIdx.x;
        if (u < 18432)        repack_one(u, w_off1, w_off1, 27, 27, 32, 1, wfo);
        else if (u < 36864)   repack_one(u - 18432, w_off2, w_off2, 27, 27, 32, 1, wfo + 18432);
        else if (u < 73728)   repack_one(u - 36864, w1, w1, 64, 64, 64, 2, wf1);
        else if (u < 110592)  repack_one(u - 73728, w2, w2, 64, 64, 64, 2, wf2);
        else if (u < 147456)  repack_one(u - 110592, w_last, w_last, 64, 64, 64, 2, wfl);
        else if (u < 147510) {
            int j = u - 147456;
            bias54[j] = (j < 27) ? b_off1[j] : b_off2[j - 27];
        }
    }
}

// ---------- conv3x3 CIN=64 (final conv), LDS-staged window, 8 waves kh-split ----------
__global__ __launch_bounds__(512, 8) void conv_stage64(
    const unsigned short* __restrict__ xn, const unsigned short* __restrict__ wf,
    const float* __restrict__ bias, float* __restrict__ out)
{
    __shared__ __align__(16) unsigned short stage[198 * 64];   // 3x66 px x 64ch
    int lb = ((blockIdx.x & 7) << 7) | (blockIdx.x >> 3);
    int t = threadIdx.x;
    int pxbase = lb * 64;
    int b = pxbase >> 14;
    int pbase = pxbase & 16383;
    int rowbase = pbase >> 7, colbase = pbase & 127;
    const unsigned short* xb = xn + ((size_t)(b << 14)) * 64;

    for (int q = t; q < 1584; q += 512) {
        int ps = q >> 3, j = q & 7;
        int ly = ps / 66, lx = ps - ly * 66;
        int y = rowbase - 1 + ly, x = colbase - 1 + lx;
        bool ok = (y >= 0) & (y < Hd) & (x >= 0) & (x < Wd);
        u32x4 v = {0, 0, 0, 0};
        if (ok) v = *(const u32x4*)(xb + ((size_t)(y * Wd + x)) * 64 + j * 8);
        *(u32x4*)(stage + ps * 64 + ((j ^ (ps & 7)) << 3)) = v;
    }
    __syncthreads();

    int lane = t & 63;
    int wave = t >> 6;
    int kh = wave >> 2;
    int wv = wave & 3;
    int sp = wv * 16 + (lane & 15);
    int px = pxbase + sp;
    int p = px & 16383;
    int cg = lane >> 4;
    int cch = kh * 4 + cg;

    const h16x8* wfv = (const h16x8*)wf;
    f32x4 acc[4];
#pragma unroll
    for (int m = 0; m < 4; m++) acc[m] = (f32x4){0.f, 0.f, 0.f, 0.f};

#pragma unroll
    for (int k = 0; k < 9; k++) {
        int ps = (k / 3) * 66 + sp + (k % 3);
        h16x8 bq = *(const h16x8*)(stage + ps * 64 + ((cch ^ (ps & 7)) << 3));
        h16x8 aF[4];
#pragma unroll
        for (int m = 0; m < 4; m++)
            aF[m] = wfv[((k * 4 + m) * 2 + kh) * 64 + lane];
#pragma unroll
        for (int m = 0; m < 4; m++)
            acc[m] = __builtin_amdgcn_mfma_f32_16x16x32_f16(aF[m], bq, acc[m], 0, 0, 0);
    }

    __syncthreads();                 // stage reads done; red aliases stage
    float* red = (float*)stage;
    if (kh == 1) {
#pragma unroll
        for (int m = 0; m < 4; m++)
#pragma unroll
            for (int j = 0; j < 4; j++)
                red[(m * 4 + j) * 256 + wv * 64 + lane] = acc[m][j];
    }
    __syncthreads();
    if (kh == 0) {
#pragma unroll
        for (int m = 0; m < 4; m++) {
            int ocb = m * 16 + cg * 4;
#pragma unroll
            for (int r = 0; r < 4; r++) {
                int oc = ocb + r;
                float v = acc[m][r] + red[(m * 4 + r) * 256 + wv * 64 + lane] + bias[oc];
                out[((size_t)b * 64 + oc) * HW + p] = v;
            }
        }
    }
}

// ---------- DCNv2 sampling helpers ----------
struct Tap { float w00, w01, w10, w11; int o00, o01, o10, o11; };

__device__ inline Tap mkparams(float oy, float ox, float mv, int row, int col, int k) {
    Tap P;
    float mk = 1.f / (1.f + __expf(-mv));
    float ys = (float)(row + k / 3 - 1) + oy;
    float xs = (float)(col + k % 3 - 1) + ox;
    float y0f = floorf(ys), x0f = floorf(xs);
    float fy = ys - y0f, fx = xs - x0f;
    int y0 = (int)y0f, x0 = (int)x0f;
    int y1 = y0 + 1, x1 = x0 + 1;
    bool vy0 = (y0 >= 0) & (y0 < Hd);
    bool vy1 = (y1 >= 0) & (y1 < Hd);
    bool vx0 = (x0 >= 0) & (x0 < Wd);
    bool vx1 = (x1 >= 0) & (x1 < Wd);
    P.w00 = (vy0 && vx0) ? (1.f - fy) * (1.f - fx) * mk : 0.f;
    P.w01 = (vy0 && vx1) ? (1.f - fy) * fx * mk : 0.f;
    P.w10 = (vy1 && vx0) ? fy * (1.f - fx) * mk : 0.f;
    P.w11 = (vy1 && vx1) ? fy * fx * mk : 0.f;
    int iy0 = min(max(y0, 0), Hd - 1) * Wd;
    int iy1 = min(max(y1, 0), Hd - 1) * Wd;
    int ix0 = min(max(x0, 0), Wd - 1);
    int ix1 = min(max(x1, 0), Wd - 1);
    P.o00 = iy0 + ix0; P.o01 = iy0 + ix1; P.o10 = iy1 + ix0; P.o11 = iy1 + ix1;
    return P;
}

// ---------- DCNv2 with FUSED offset-conv (R15 serial phases) + packed b128 tap table ----------
// tbl[s*4 + {0,1,2,3}] = {a01, a23, w01, w23}; one ds_read_b128 per tap in main loop.
// code = inw ? (ps<<3)|(ps&7) : 0x8000|o ; lds byte = ((code&0xFFF)^cch)<<4 ; fb o = code&0x7fff
// EPI 0: leaky -> outn. EPI 1: + residn (NHWC fp16) -> outn.
template<int EPI>
__global__ __launch_bounds__(512, 4) void dcn_fused(
    const unsigned short* __restrict__ xn, const unsigned short* __restrict__ offn,
    const unsigned short* __restrict__ wfo, const float* __restrict__ obias,
    const unsigned short* __restrict__ wf, const float* __restrict__ bias,
    const unsigned short* __restrict__ residn, unsigned short* __restrict__ outn)
{
    __shared__ __align__(16) unsigned short stage[490 * 64];  // 62.7KB main window
    __shared__ __align__(16) unsigned tbl[576 * 4];           // packed tap records (9.2KB)

    unsigned short* offstage = stage;           // 198*32 ush = 12672B (slots 0..98)
    float* omt = (float*)(stage + 6336);        // 27*64 f32 = 6912B (dead before main fill)

    int lb = ((blockIdx.x & 7) << 7) | (blockIdx.x >> 3);
    int t = threadIdx.x;
    int pxbase = lb * 64;
    int b = pxbase >> 14;
    int pbase = pxbase & 16383;
    int rowbase = pbase >> 7;
    int colbase = pbase & 127;
    int ybase = rowbase - 3;
    int xbase = colbase - 3;
    const unsigned short* xb = xn + ((size_t)(b << 14)) * 64;
    const unsigned short* ob = offn + ((size_t)(b << 14)) * 32;

    // ---- phase 0a: stage offn 3x66 window ----
    for (int q = t; q < 792; q += 512) {
        int ps = q >> 2, j = q & 3;
        int ly = ps / 66, lx = ps - ly * 66;
        int y = rowbase - 1 + ly, x = colbase - 1 + lx;
        bool ok = (y >= 0) & (y < Hd) & (x >= 0) & (x < Wd);
        u32x4 v = {0, 0, 0, 0};
        if (ok) v = *(const u32x4*)(ob + ((size_t)(y * Wd + x)) * 32 + j * 8);
        *(u32x4*)(offstage + ps * 32 + ((j ^ (ps & 3)) << 3)) = v;
    }
    __syncthreads();

    int lane = t & 63;
    int wave = t >> 6;

    // ---- phase 0b: offset conv, waves 0-3 (27 oc, m-tiles 0..1) ----
    if (wave < 4) {
        int osp = wave * 16 + (lane & 15);
        int cg4 = lane >> 4;
        const h16x8* wfv = (const h16x8*)wfo;
        f32x4 oacc[2];
#pragma unroll
        for (int m = 0; m < 2; m++) oacc[m] = (f32x4){0.f, 0.f, 0.f, 0.f};
#pragma unroll
        for (int k = 0; k < 9; k++) {
            int ps = (k / 3) * 66 + osp + (k % 3);
            h16x8 bq = *(const h16x8*)(offstage + ps * 32 + ((cg4 ^ (ps & 3)) << 3));
#pragma unroll
            for (int m = 0; m < 2; m++) {
                h16x8 aF = wfv[(k * 4 + m) * 64 + lane];
                oacc[m] = __builtin_amdgcn_mfma_f32_16x16x32_f16(aF, bq, oacc[m], 0, 0, 0);
            }
        }
#pragma unroll
        for (int m = 0; m < 2; m++) {
            int ocb = m * 16 + cg4 * 4;
#pragma unroll
            for (int r = 0; r < 4; r++) {
                int oc = ocb + r;
                if (oc < 27) omt[oc * 64 + osp] = oacc[m][r] + obias[oc];
            }
        }
    }
    __syncthreads();

    // ---- phase 1a: tap params from omt -> packed b128 records ----
    for (int s = t; s < 576; s += 512) {
        int k = s >> 6, sp2 = s & 63;
        int row = rowbase, col = colbase + sp2;
        float oy = omt[(2 * k) * 64 + sp2];
        float ox = omt[(2 * k + 1) * 64 + sp2];
        float mv = omt[(18 + k) * 64 + sp2];
        Tap P = mkparams(oy, ox, mv, row, col, k);

        unsigned a[4];
        int oo[4] = {P.o00, P.o01, P.o10, P.o11};
#pragma unroll
        for (int c = 0; c < 4; c++) {
            int o = oo[c];
            int y = o >> 7, x = o & 127;
            int ly = y - ybase, lx = x - xbase;
            bool inw = ((unsigned)ly < 7u) & ((unsigned)lx < 70u);
            int ps = min(max(ly, 0), 6) * 70 + min(max(lx, 0), 69);
            a[c] = inw ? (unsigned)((ps << 3) | (ps & 7)) : (0x8000u | (unsigned)o);
        }
        u32x4 pk4 = { a[0] | (a[1] << 16),
                      a[2] | (a[3] << 16),
                      (unsigned)f2h(P.w00) | ((unsigned)f2h(P.w01) << 16),
                      (unsigned)f2h(P.w10) | ((unsigned)f2h(P.w11) << 16) };
        *(u32x4*)&tbl[s * 4] = pk4;
    }
    __syncthreads();   // omt/offstage reads done; safe to overwrite stage

    // ---- phase 1b: fill main 7x70 stage ----
    for (int q = t; q < 3920; q += 512) {
        int ps = q >> 3, j = q & 7;
        int ly = ps / 70, lx = ps - ly * 70;
        int y = min(max(ybase + ly, 0), Hd - 1);
        int x = min(max(xbase + lx, 0), Wd - 1);
        u32x4 v = *(const u32x4*)(xb + ((size_t)(y * Wd + x)) * 64 + j * 8);
        *(u32x4*)(stage + ps * 64 + ((j ^ (ps & 7)) << 3)) = v;
    }
    __syncthreads();

    int kh = wave >> 2;
    int wv = wave & 3;
    int sp = wv * 16 + (lane & 15);
    int px = pxbase + sp;
    int cg = lane >> 4;
    int c0 = kh * 32 + cg * 8;
    int cch = kh * 4 + cg;

    const h16x8* wfv = (const h16x8*)wf;

    f32x4 acc[4];
#pragma unroll
    for (int m = 0; m < 4; m++) acc[m] = (f32x4){0.f, 0.f, 0.f, 0.f};

#pragma unroll
    for (int k = 0; k < 9; k++) {
        int s = k * 64 + sp;
        u32x4 tv = *(const u32x4*)&tbl[s * 4];
        unsigned a01 = tv[0], a23 = tv[1], w01 = tv[2], w23 = tv[3];

        unsigned code[4] = { a01 & 0xffffu, a01 >> 16, a23 & 0xffffu, a23 >> 16 };
        h16x8 gc[4];
#pragma unroll
        for (int c = 0; c < 4; c++)
            gc[c] = *(const h16x8*)((const char*)stage + (((code[c] & 0xFFFu) ^ (unsigned)cch) << 4));

        if (__builtin_expect((a01 | a23) & 0x80008000u, 0)) {
#pragma unroll
            for (int c = 0; c < 4; c++)
                if (code[c] & 0x8000u)
                    gc[c] = *(const h16x8*)(xb + (size_t)(code[c] & 0x7fffu) * 64 + c0);
        }

        _Float16 h00 = u2h((unsigned short)(w01 & 0xffffu));
        _Float16 h01 = u2h((unsigned short)(w01 >> 16));
        _Float16 h10 = u2h((unsigned short)(w23 & 0xffffu));
        _Float16 h11 = u2h((unsigned short)(w23 >> 16));
        h16x8 bF = gc[0] * h00;
        bF = gc[1] * h01 + bF;
        bF = gc[2] * h10 + bF;
        bF = gc[3] * h11 + bF;

        h16x8 aF[4];
#pragma unroll
        for (int m = 0; m < 4; m++)
            aF[m] = wfv[((k * 4 + m) * 2 + kh) * 64 + lane];
#pragma unroll
        for (int m = 0; m < 4; m++)
            acc[m] = __builtin_amdgcn_mfma_f32_16x16x32_f16(aF[m], bF, acc[m], 0, 0, 0);
    }

    __syncthreads();
    float* red = (float*)stage;
    if (kh == 1) {
#pragma unroll
        for (int m = 0; m < 4; m++)
#pragma unroll
            for (int j = 0; j < 4; j++)
                red[(m * 4 + j) * 256 + wv * 64 + lane] = acc[m][j];
    }
    __syncthreads();
    if (kh == 0) {
        unsigned short* drow = outn + (size_t)px * 64;
        const unsigned short* rrow = (EPI == 1) ? residn + (size_t)px * 64 : nullptr;
#pragma unroll
        for (int m = 0; m < 4; m++) {
            int ocb = m * 16 + cg * 4;
            float rv[4] = {0.f, 0.f, 0.f, 0.f};
            if (EPI == 1) {
                ushort4 rr = *(const ushort4*)(rrow + ocb);
                rv[0] = (float)u2h(rr.x); rv[1] = (float)u2h(rr.y);
                rv[2] = (float)u2h(rr.z); rv[3] = (float)u2h(rr.w);
            }
            unsigned short pk[4];
#pragma unroll
            for (int r = 0; r < 4; r++) {
                int oc = ocb + r;
                float v = acc[m][r] + red[(m * 4 + r) * 256 + wv * 64 + lane] + bias[oc];
                if (EPI == 0) v = (v >= 0.f) ? v : 0.01f * v;
                if (EPI == 1) v += rv[r];
                pk[r] = f2h(v);
            }
            *(ushort4*)(drow + ocb) = *(ushort4*)pk;
        }
    }
}

extern "C" void kernel_launch(void* const* d_in, const int* in_sizes, int n_in,
                              void* d_out, int out_size, void* d_ws, size_t ws_size,
                              hipStream_t stream)
{
    const float* input  = (const float*)d_in[0];
    const float* offset = (const float*)d_in[1];
    const float* w_off1 = (const float*)d_in[2];
    const float* b_off1 = (const float*)d_in[3];
    const float* w1     = (const float*)d_in[4];
    const float* b1     = (const float*)d_in[5];
    const float* w_off2 = (const float*)d_in[6];
    const float* b_off2 = (const float*)d_in[7];
    const float* w2     = (const float*)d_in[8];
    const float* b2     = (const float*)d_in[9];
    const float* w_last = (const float*)d_in[10];
    const float* b_last = (const float*)d_in[11];
    float* out = (float*)d_out;

    unsigned short* xn   = (unsigned short*)d_ws;          // 4,194,304 ush
    unsigned short* offn = xn + 4194304;                   // 2,097,152 ush
    unsigned short* x1n  = offn + 2097152;                 // 4,194,304 ush
    unsigned short* x2n  = x1n + 4194304;                  // 4,194,304 ush
    unsigned short* wfo  = x2n + 4194304;                  // 36,864 ush (two 27-oc sets)
    unsigned short* wf1  = wfo + 36864;                    // 36,864 ush
    unsigned short* wf2  = wf1 + 36864;                    // 36,864 ush
    unsigned short* wfl  = wf2 + 36864;                    // 36,864 ush
    float* bias54 = (float*)(wfl + 36864);                 // 64 f

    prep<<<dim3(1089), 256, 0, stream>>>(input, offset, w_off1, w_off2, b_off1, b_off2,
                                         w1, w2, w_last, xn, offn, wfo, wf1, wf2, wfl, bias54);

    // DCN 1 (fused offset-conv set 0): sample xn, leaky -> x1n
    dcn_fused<0><<<dim3(1024), 512, 0, stream>>>(xn, offn, wfo, bias54,
                                                 wf1, b1, nullptr, x1n);
    // DCN 2 (fused offset-conv set 1): sample x1n, + xn residual (fp16 NHWC) -> x2n
    dcn_fused<1><<<dim3(1024), 512, 0, stream>>>(x1n, offn, wfo + 18432, bias54 + 27,
                                                 wf2, b2, xn, x2n);
    // final conv
    conv_stage64<<<dim3(1024), 512, 0, stream>>>(x2n, wfl, b_last, out);
}